// Round 1
// baseline (110.360 us; speedup 1.0000x reference)
//
#include <hip/hip_runtime.h>

// Problem constants
#define NB 2048     // batch
#define NN 64       // nodes
#define KFIN 96
#define KFOUT 128
#define KOPD 48

typedef __attribute__((ext_vector_type(8))) short bf8;      // 8 bf16 (4 VGPRs) MFMA A/B frag
typedef __attribute__((ext_vector_type(4))) float f32x4;    // MFMA C/D frag
typedef __attribute__((ext_vector_type(4))) unsigned short us4;

__device__ __forceinline__ unsigned short f2bf(float f) {   // f32 -> bf16 RNE
  unsigned int u = __builtin_bit_cast(unsigned int, f);
  u += 0x7fffu + ((u >> 16) & 1u);
  return (unsigned short)(u >> 16);
}
__device__ __forceinline__ float bf2f(unsigned short s) {
  unsigned int u = ((unsigned int)s) << 16;
  return __builtin_bit_cast(float, u);
}
__device__ __forceinline__ us4 pack4(float a, float b, float c, float d) {
  us4 q; q.x = f2bf(a); q.y = f2bf(b); q.z = f2bf(c); q.w = f2bf(d); return q;
}

// ws layout (ushort): WT[128][96]@0, WkT[128][96]@12288,
// WopdT[128][64]@24576 (k 48..63 zero), WopgT[128][64]@32768. total 40960 elems.
__global__ void prep_weights(const float* __restrict__ W, const float* __restrict__ Wk,
                             const float* __restrict__ Wd, const float* __restrict__ Wg,
                             unsigned short* __restrict__ ws) {
  int idx = blockIdx.x * 256 + threadIdx.x;
  if (idx >= 40960) return;
  float v;
  if (idx < 12288)      { int o = idx / 96, f = idx % 96; v = W[f * 128 + o]; }
  else if (idx < 24576) { int r = idx - 12288; int o = r / 96, f = r % 96; v = Wk[f * 128 + o]; }
  else if (idx < 32768) { int r = idx - 24576; int o = r >> 6, k = r & 63; v = (k < 48) ? Wd[k * 128 + o] : 0.f; }
  else                  { int r = idx - 32768; int o = r >> 6, k = r & 63; v = (k < 48) ? Wg[k * 128 + o] : 0.f; }
  ws[idx] = f2bf(v);
}

// One block per batch element. 256 threads = 4 waves; wave w owns output rows [w*16, w*16+16).
// LDS plan (49 KB):
//   [0,13312)      h[64][104]          -> dead after G2; overlaid by whkT
//   [13312,22528)  ope[64][72]         -> dead after G3g; overlaid by whkT
//   [22528,31744)  adj[64][72]         -> becomes attn in-place (per-wave row-block swap)
//   [31744,50176)  supT[128][72]       -> dead after G4; becomes whk[64][136] row-major
//   whkT[128][72] @0 (18432B <= 22528) written after barrier2
__global__ __launch_bounds__(256, 2) void gin_fused(
    const float* __restrict__ hg, const float* __restrict__ adjg,
    const float* __restrict__ opeg, const float* __restrict__ bvec,
    const float* __restrict__ bopd, const float* __restrict__ bopg,
    const float* __restrict__ awv, const float* __restrict__ gmv,
    const float* __restrict__ btv, const unsigned short* __restrict__ ws,
    float* __restrict__ out) {
  __shared__ __align__(16) char smem[50176];
  unsigned short* h_s   = (unsigned short*)smem;             // [64][104]
  unsigned short* ope_s = (unsigned short*)(smem + 13312);   // [64][72]
  unsigned short* adj_s = (unsigned short*)(smem + 22528);   // [64][72] -> attn
  unsigned short* supT  = (unsigned short*)(smem + 31744);   // [128][72]
  unsigned short* whkT  = (unsigned short*)smem;             // [128][72] overlay
  unsigned short* whk   = supT;                              // [64][136] row-major overlay

  const int t  = threadIdx.x;
  const int b  = blockIdx.x;
  const int w  = t >> 6;
  const int l  = t & 63;
  const int lr = l & 15;       // A-row / B-row / C-col lane index
  const int lg = l >> 4;       // k-group / C-row group
  const int kcol = 8 * lg;
  const int arow = w * 16 + lr;

  // ---------------- stage h, adj, op_emb (f32 -> bf16) ----------------
  {
    const float4* p = (const float4*)(hg + (size_t)b * (NN * KFIN));
    #pragma unroll
    for (int i = 0; i < 6; ++i) {
      int idx = t + i * 256;
      float4 v = p[idx];
      int e = idx * 4, r = e / 96, c = e - r * 96;
      *(us4*)(h_s + r * 104 + c) = pack4(v.x, v.y, v.z, v.w);
    }
    const float4* pa = (const float4*)(adjg + (size_t)b * (NN * NN));
    #pragma unroll
    for (int i = 0; i < 4; ++i) {
      int idx = t + i * 256;
      float4 v = pa[idx];
      int e = idx * 4, r = e >> 6, c = e & 63;
      *(us4*)(adj_s + r * 72 + c) = pack4(v.x, v.y, v.z, v.w);
    }
    const float4* po = (const float4*)(opeg + (size_t)b * (NN * KOPD));
    #pragma unroll
    for (int i = 0; i < 3; ++i) {
      int idx = t + i * 256;
      float4 v = po[idx];
      int e = idx * 4, r = e / 48, c = e - r * 48;
      *(us4*)(ope_s + r * 72 + c) = pack4(v.x, v.y, v.z, v.w);
    }
    us4 z; z.x = 0; z.y = 0; z.z = 0; z.w = 0;   // zero-pad ope k=48..63
    *(us4*)(ope_s + (t >> 2) * 72 + 48 + (t & 3) * 4) = z;
  }
  __syncthreads();   // barrier0

  const unsigned short* WT  = ws;
  const unsigned short* WkT = ws + 12288;
  const unsigned short* WdT = ws + 24576;
  const unsigned short* WgT = ws + 32768;
  f32x4 zz = {0.f, 0.f, 0.f, 0.f};

  // ---------------- G1: support = h @ W (K=96) ----------------
  f32x4 sacc[8] = {zz, zz, zz, zz, zz, zz, zz, zz};
  #pragma unroll
  for (int kb = 0; kb < 3; ++kb) {
    bf8 a = *(const bf8*)(h_s + arow * 104 + kb * 32 + kcol);
    #pragma unroll
    for (int nb = 0; nb < 8; ++nb) {
      bf8 bb = *(const bf8*)(WT + (nb * 16 + lr) * 96 + kb * 32 + kcol);
      sacc[nb] = __builtin_amdgcn_mfma_f32_16x16x32_bf16(a, bb, sacc[nb], 0, 0, 0);
    }
  }
  // write support^T bf16 (B operand for G4): lane writes 4 contiguous j at row o
  #pragma unroll
  for (int nb = 0; nb < 8; ++nb)
    *(us4*)(supT + (nb * 16 + lr) * 72 + w * 16 + lg * 4) =
        pack4(sacc[nb][0], sacc[nb][1], sacc[nb][2], sacc[nb][3]);

  // ---------------- G3d: gate_d = sigmoid(ope @ Wop_d + bop_d) (K padded to 64) ----------------
  f32x4 gd[8] = {zz, zz, zz, zz, zz, zz, zz, zz};
  #pragma unroll
  for (int kb = 0; kb < 2; ++kb) {
    bf8 a = *(const bf8*)(ope_s + arow * 72 + kb * 32 + kcol);
    #pragma unroll
    for (int nb = 0; nb < 8; ++nb) {
      bf8 bb = *(const bf8*)(WdT + (nb * 16 + lr) * 64 + kb * 32 + kcol);
      gd[nb] = __builtin_amdgcn_mfma_f32_16x16x32_bf16(a, bb, gd[nb], 0, 0, 0);
    }
  }
  #pragma unroll
  for (int nb = 0; nb < 8; ++nb) {
    float bo = bopd[nb * 16 + lr];
    #pragma unroll
    for (int r = 0; r < 4; ++r) gd[nb][r] = 1.f / (1.f + __expf(-(gd[nb][r] + bo)));
  }
  __syncthreads();   // barrier1: supT visible

  // ---------------- G4: agg = adj @ support ; dense = gate_d*agg + support + b ----------------
  {
    f32x4 dacc[8] = {zz, zz, zz, zz, zz, zz, zz, zz};
    #pragma unroll
    for (int kb = 0; kb < 2; ++kb) {
      bf8 a = *(const bf8*)(adj_s + arow * 72 + kb * 32 + kcol);
      #pragma unroll
      for (int nb = 0; nb < 8; ++nb) {
        bf8 bb = *(const bf8*)(supT + (nb * 16 + lr) * 72 + kb * 32 + kcol);
        dacc[nb] = __builtin_amdgcn_mfma_f32_16x16x32_bf16(a, bb, dacc[nb], 0, 0, 0);
      }
    }
    #pragma unroll
    for (int nb = 0; nb < 8; ++nb) {
      float bc = bvec[nb * 16 + lr];
      #pragma unroll
      for (int r = 0; r < 4; ++r)
        sacc[nb][r] = gd[nb][r] * dacc[nb][r] + sacc[nb][r] + bc;   // sacc := dense
    }
  }

  // ---------------- G2: Whk = h @ Wk ----------------
  f32x4 wacc[8] = {zz, zz, zz, zz, zz, zz, zz, zz};
  #pragma unroll
  for (int kb = 0; kb < 3; ++kb) {
    bf8 a = *(const bf8*)(h_s + arow * 104 + kb * 32 + kcol);
    #pragma unroll
    for (int nb = 0; nb < 8; ++nb) {
      bf8 bb = *(const bf8*)(WkT + (nb * 16 + lr) * 96 + kb * 32 + kcol);
      wacc[nb] = __builtin_amdgcn_mfma_f32_16x16x32_bf16(a, bb, wacc[nb], 0, 0, 0);
    }
  }

  // ---------------- G3g: gate_g ----------------
  f32x4 gg[8] = {zz, zz, zz, zz, zz, zz, zz, zz};
  #pragma unroll
  for (int kb = 0; kb < 2; ++kb) {
    bf8 a = *(const bf8*)(ope_s + arow * 72 + kb * 32 + kcol);
    #pragma unroll
    for (int nb = 0; nb < 8; ++nb) {
      bf8 bb = *(const bf8*)(WgT + (nb * 16 + lr) * 64 + kb * 32 + kcol);
      gg[nb] = __builtin_amdgcn_mfma_f32_16x16x32_bf16(a, bb, gg[nb], 0, 0, 0);
    }
  }
  #pragma unroll
  for (int nb = 0; nb < 8; ++nb) {
    float bo = bopg[nb * 16 + lr];
    #pragma unroll
    for (int r = 0; r < 4; ++r) gg[nb][r] = 1.f / (1.f + __expf(-(gg[nb][r] + bo)));
  }
  __syncthreads();   // barrier2: all waves done reading h, ope, supT

  // ---------------- write Whk row-major [64][136] and transposed [128][72] ----------------
  #pragma unroll
  for (int nb = 0; nb < 8; ++nb) {
    int o = nb * 16 + lr;
    *(us4*)(whkT + o * 72 + w * 16 + lg * 4) =
        pack4(wacc[nb][0], wacc[nb][1], wacc[nb][2], wacc[nb][3]);
    #pragma unroll
    for (int r = 0; r < 4; ++r)
      whk[(w * 16 + lg * 4 + r) * 136 + o] = f2bf(wacc[nb][r]);
  }
  __syncthreads();   // barrier3: whk + whkT visible

  // ---------------- G5: scores = (Whk * a_w) @ Whk^T (K=128) ----------------
  f32x4 sc[4] = {zz, zz, zz, zz};
  #pragma unroll
  for (int kb = 0; kb < 4; ++kb) {
    bf8 ar = *(const bf8*)(whk + arow * 136 + kb * 32 + kcol);
    const float4* ap = (const float4*)(awv + kb * 32 + kcol);
    float4 a0 = ap[0], a1 = ap[1];
    bf8 a;
    a[0] = (short)f2bf(bf2f((unsigned short)ar[0]) * a0.x);
    a[1] = (short)f2bf(bf2f((unsigned short)ar[1]) * a0.y);
    a[2] = (short)f2bf(bf2f((unsigned short)ar[2]) * a0.z);
    a[3] = (short)f2bf(bf2f((unsigned short)ar[3]) * a0.w);
    a[4] = (short)f2bf(bf2f((unsigned short)ar[4]) * a1.x);
    a[5] = (short)f2bf(bf2f((unsigned short)ar[5]) * a1.y);
    a[6] = (short)f2bf(bf2f((unsigned short)ar[6]) * a1.z);
    a[7] = (short)f2bf(bf2f((unsigned short)ar[7]) * a1.w);
    #pragma unroll
    for (int jb = 0; jb < 4; ++jb) {
      bf8 bb = *(const bf8*)(whk + (jb * 16 + lr) * 136 + kb * 32 + kcol);
      sc[jb] = __builtin_amdgcn_mfma_f32_16x16x32_bf16(a, bb, sc[jb], 0, 0, 0);
    }
  }

  // ---------------- softmax over j (leaky_relu * adj, exact reference semantics) ----------------
  const int rowb = w * 16 + lg * 4;
  float al[4][4];
  #pragma unroll
  for (int jb = 0; jb < 4; ++jb)
    #pragma unroll
    for (int r = 0; r < 4; ++r) {
      float s = sc[jb][r];
      float am = bf2f(adj_s[(rowb + r) * 72 + jb * 16 + lr]);   // all adj reads before any attn write
      al[jb][r] = (s >= 0.f ? s : 0.01f * s) * am;
    }
  #pragma unroll
  for (int r = 0; r < 4; ++r) {
    float m = fmaxf(fmaxf(al[0][r], al[1][r]), fmaxf(al[2][r], al[3][r]));
    m = fmaxf(m, __shfl_xor(m, 1));
    m = fmaxf(m, __shfl_xor(m, 2));
    m = fmaxf(m, __shfl_xor(m, 4));
    m = fmaxf(m, __shfl_xor(m, 8));
    float s0 = 0.f;
    #pragma unroll
    for (int jb = 0; jb < 4; ++jb) { float p = __expf(al[jb][r] - m); al[jb][r] = p; s0 += p; }
    s0 += __shfl_xor(s0, 1);
    s0 += __shfl_xor(s0, 2);
    s0 += __shfl_xor(s0, 4);
    s0 += __shfl_xor(s0, 8);
    float inv = 1.f / s0;
    #pragma unroll
    for (int jb = 0; jb < 4; ++jb) al[jb][r] *= inv;
  }
  #pragma unroll
  for (int jb = 0; jb < 4; ++jb)
    #pragma unroll
    for (int r = 0; r < 4; ++r)
      adj_s[(rowb + r) * 72 + jb * 16 + lr] = f2bf(al[jb][r]);  // attn in place of adj (own rows only)

  // ---------------- G6: hp = attn @ Whk (reads only this wave's attn rows) ----------------
  f32x4 hpacc[8] = {zz, zz, zz, zz, zz, zz, zz, zz};
  #pragma unroll
  for (int kb = 0; kb < 2; ++kb) {
    bf8 a = *(const bf8*)(adj_s + arow * 72 + kb * 32 + kcol);
    #pragma unroll
    for (int nb = 0; nb < 8; ++nb) {
      bf8 bb = *(const bf8*)(whkT + (nb * 16 + lr) * 72 + kb * 32 + kcol);
      hpacc[nb] = __builtin_amdgcn_mfma_f32_16x16x32_bf16(a, bb, hpacc[nb], 0, 0, 0);
    }
  }

  // ---------------- gate_g * hp, LayerNorm, combine, store ----------------
  float gam[8], bet[8];
  #pragma unroll
  for (int nb = 0; nb < 8; ++nb) { gam[nb] = gmv[nb * 16 + lr]; bet[nb] = btv[nb * 16 + lr]; }
  float* outp = out + (size_t)b * (NN * KFOUT);
  #pragma unroll
  for (int r = 0; r < 4; ++r) {
    float hv[8]; float su = 0.f, sq = 0.f;
    #pragma unroll
    for (int nb = 0; nb < 8; ++nb) {
      float v = gg[nb][r] * hpacc[nb][r];
      hv[nb] = v; su += v; sq += v * v;
    }
    su += __shfl_xor(su, 1); su += __shfl_xor(su, 2);
    su += __shfl_xor(su, 4); su += __shfl_xor(su, 8);
    sq += __shfl_xor(sq, 1); sq += __shfl_xor(sq, 2);
    sq += __shfl_xor(sq, 4); sq += __shfl_xor(sq, 8);
    float mean = su * (1.f / 128.f);
    float var  = sq * (1.f / 128.f) - mean * mean;
    float rinv = rsqrtf(var + 1e-5f);
    int row = rowb + r;
    #pragma unroll
    for (int nb = 0; nb < 8; ++nb) {
      float hn = (hv[nb] - mean) * rinv * gam[nb] + bet[nb];
      outp[row * 128 + nb * 16 + lr] = (sacc[nb][r] + hn) * 0.5f;
    }
  }
}

extern "C" void kernel_launch(void* const* d_in, const int* in_sizes, int n_in,
                              void* d_out, int out_size, void* d_ws, size_t ws_size,
                              hipStream_t stream) {
  const float* h     = (const float*)d_in[0];
  const float* adj   = (const float*)d_in[1];
  const float* ope   = (const float*)d_in[2];
  const float* W     = (const float*)d_in[3];
  const float* bvec  = (const float*)d_in[4];
  const float* Wopd  = (const float*)d_in[5];
  const float* bopd  = (const float*)d_in[6];
  const float* Wk    = (const float*)d_in[7];
  const float* a_w   = (const float*)d_in[8];
  const float* Wopg  = (const float*)d_in[9];
  const float* bopg  = (const float*)d_in[10];
  const float* gamma = (const float*)d_in[11];
  const float* beta  = (const float*)d_in[12];
  float* out = (float*)d_out;
  unsigned short* ws = (unsigned short*)d_ws;

  prep_weights<<<dim3(160), dim3(256), 0, stream>>>(W, Wk, Wopd, Wopg, ws);
  gin_fused<<<dim3(NB), dim3(256), 0, stream>>>(h, adj, ope, bvec, bopd, bopg,
                                                a_w, gamma, beta, ws, out);
}